// Round 16
// baseline (97.622 us; speedup 1.0000x reference)
//
#include <hip/hip_runtime.h>
#include <cstdint>
#include <cstddef>

#define NB 4
#define NS 2048
#define ND 512
#define NH 8
#define DH 64
#define MTOK (NB*NS)

typedef __bf16 bf16x8 __attribute__((ext_vector_type(8)));
typedef float f32x4 __attribute__((ext_vector_type(4)));
typedef float f32x16 __attribute__((ext_vector_type(16)));
typedef unsigned int u32x4 __attribute__((ext_vector_type(4)));
typedef unsigned short ushort_t;
typedef unsigned int uint_t;

__device__ __forceinline__ unsigned short f2bf(float f) {
  unsigned int u = __builtin_bit_cast(unsigned int, f);
  return (unsigned short)((u + 0x7fffu + ((u >> 16) & 1u)) >> 16);
}

__device__ __forceinline__ uint_t cvtpk(float lo, float hi) {
  uint_t r;
  asm("v_cvt_pk_bf16_f32 %0, %1, %2" : "=v"(r) : "v"(lo), "v"(hi));
  return r;
}

// swap lanes 32-63 of a with lanes 0-31 of b (only used on distinct values)
__device__ __forceinline__ void pswap(uint_t &a, uint_t &b) {
  asm("v_permlane32_swap_b32 %0, %1" : "+v"(a), "+v"(b));
}

__device__ __forceinline__ void gload_lds16(const void* g, void* l) {
  __builtin_amdgcn_global_load_lds(
      (const __attribute__((address_space(1))) unsigned int*)g,
      (__attribute__((address_space(3))) unsigned int*)l,
      16, 0, 0);
}

__device__ __forceinline__ bf16x8 ld8(const ushort_t* p) { return *(const bf16x8*)p; }

// ---------------- fused LayerNorm (blocks 0..2047) + weight convert (2048..2559) ----
__global__ __launch_bounds__(256) void ln_conv(
    const float* __restrict__ x, const float* __restrict__ gamma,
    const float* __restrict__ beta, ushort_t* __restrict__ xn,
    const float* __restrict__ Wq, const float* __restrict__ Wk,
    const float* __restrict__ Wv, const float* __restrict__ Wo,
    ushort_t* __restrict__ wqkv, ushort_t* __restrict__ wob)
{
  if (blockIdx.x >= 2048) {
    const int t = (blockIdx.x - 2048)*256 + threadIdx.x;
    const int i = t*8;
    const float* src; ushort_t* dst;
    if (i < 1536*512) {
      const int n = i >> 9, c = i & 511;
      const float* W = (n < 512) ? Wq : (n < 1024) ? Wk : Wv;
      src = W + ((size_t)(n & 511) << 9) + c;
      dst = wqkv + i;
    } else {
      const int jj = i - 1536*512;
      src = Wo + jj; dst = wob + jj;
    }
    float4 a = ((const float4*)src)[0], b = ((const float4*)src)[1];
    uint4 o;
    o.x = (uint_t)f2bf(a.x) | ((uint_t)f2bf(a.y)<<16);
    o.y = (uint_t)f2bf(a.z) | ((uint_t)f2bf(a.w)<<16);
    o.z = (uint_t)f2bf(b.x) | ((uint_t)f2bf(b.y)<<16);
    o.w = (uint_t)f2bf(b.z) | ((uint_t)f2bf(b.w)<<16);
    *(uint4*)dst = o;
    return;
  }
  const int row  = blockIdx.x * 4 + (threadIdx.x >> 6);
  const int lane = threadIdx.x & 63;
  const float4* xr = (const float4*)(x + (size_t)row * ND);
  float4 a = xr[lane*2], b = xr[lane*2+1];
  float v[8] = {a.x,a.y,a.z,a.w,b.x,b.y,b.z,b.w};
  float s = 0.f, s2 = 0.f;
#pragma unroll
  for (int j = 0; j < 8; ++j) { s += v[j]; s2 += v[j]*v[j]; }
#pragma unroll
  for (int mk = 1; mk < 64; mk <<= 1) { s += __shfl_xor(s, mk); s2 += __shfl_xor(s2, mk); }
  const float mu = s * (1.0f/ND);
  const float rs = rsqrtf(s2*(1.0f/ND) - mu*mu + 1e-5f);
  const float4* g4 = (const float4*)gamma;
  const float4* b4 = (const float4*)beta;
  float4 g0 = g4[lane*2], g1 = g4[lane*2+1];
  float4 e0 = b4[lane*2], e1 = b4[lane*2+1];
  float gv[8] = {g0.x,g0.y,g0.z,g0.w,g1.x,g1.y,g1.z,g1.w};
  float ev[8] = {e0.x,e0.y,e0.z,e0.w,e1.x,e1.y,e1.z,e1.w};
  unsigned short o[8];
#pragma unroll
  for (int j = 0; j < 8; ++j) o[j] = f2bf((v[j]-mu)*rs*gv[j] + ev[j]);
  uint4 ov;
  ov.x = (uint_t)o[0] | ((uint_t)o[1]<<16);
  ov.y = (uint_t)o[2] | ((uint_t)o[3]<<16);
  ov.z = (uint_t)o[4] | ((uint_t)o[5]<<16);
  ov.w = (uint_t)o[6] | ((uint_t)o[7]<<16);
  ((uint4*)(xn + (size_t)row*ND))[lane] = ov;
}

// ---------------- GEMM C[M,N] = A[M,K] * Bw[N,K]^T, 128x128 tile, BK=32 ----------------
// Double-buffered LDS; counted vmcnt; 1-D grid with XCD-bijective swizzle so each
// XCD works a contiguous m-panel band (B + A-panels fit its private L2).
// EPI==0 scatters q/k/v into fragment layouts.
template<int EPI, int NTN>
__global__ __launch_bounds__(256, 2) void gemm_bt(
    const ushort_t* __restrict__ A, const ushort_t* __restrict__ Bw, int Kd,
    const float* __restrict__ bq, const float* __restrict__ bk, const float* __restrict__ bv,
    ushort_t* __restrict__ qa, ushort_t* __restrict__ ka, ushort_t* __restrict__ vta,
    const float* __restrict__ bo, float* __restrict__ outp)
{
  __shared__ ushort_t lA[2][128*32];
  __shared__ ushort_t lB[2][128*32];
  const int tid = threadIdx.x;
  const int wave = tid >> 6, lane = tid & 63;
  const int wg = (blockIdx.x & 7) * (gridDim.x >> 3) + (blockIdx.x >> 3);
  const int m0 = (wg / NTN) * 128, n0 = (wg % NTN) * 128;
  const int wr = (wave >> 1) * 64, wc = (wave & 1) * 64;

  f32x4 acc[4][4] = {};

  const ushort_t* aS = A  + (size_t)(m0 + tid/4) * Kd + (tid & 3) * 8;
  const ushort_t* bS = Bw + (size_t)(n0 + tid/4) * Kd + (tid & 3) * 8;
  const size_t half = (size_t)64 * Kd;
  const int NT = Kd / 32;

#define STAGE(BUF, K0)                                            \
  gload_lds16(aS + (K0),        lA[BUF] + wave*512);              \
  gload_lds16(aS + half + (K0), lA[BUF] + 2048 + wave*512);       \
  gload_lds16(bS + (K0),        lB[BUF] + wave*512);              \
  gload_lds16(bS + half + (K0), lB[BUF] + 2048 + wave*512);

  STAGE(0, 0);
  int cur = 0;
  for (int t = 0; t < NT; ++t) {
    if (t + 1 < NT) {
      STAGE(cur ^ 1, (t + 1) * 32);
      asm volatile("s_waitcnt vmcnt(4)" ::: "memory");
    } else {
      asm volatile("s_waitcnt vmcnt(0)" ::: "memory");
    }
    __builtin_amdgcn_s_barrier();
    asm volatile("" ::: "memory");
    bf16x8 af[4], bfr[4];
#pragma unroll
    for (int i = 0; i < 4; ++i)
      af[i] = *(const bf16x8*)(lA[cur] + (wr + i*16 + (lane&15))*32 + (lane>>4)*8);
#pragma unroll
    for (int j = 0; j < 4; ++j)
      bfr[j] = *(const bf16x8*)(lB[cur] + (wc + j*16 + (lane&15))*32 + (lane>>4)*8);
#pragma unroll
    for (int i = 0; i < 4; ++i)
#pragma unroll
      for (int j = 0; j < 4; ++j)
        acc[i][j] = __builtin_amdgcn_mfma_f32_16x16x32_bf16(af[i], bfr[j], acc[i][j], 0, 0, 0);
    asm volatile("s_waitcnt lgkmcnt(0)" ::: "memory");
    __builtin_amdgcn_s_barrier();
    asm volatile("" ::: "memory");
    cur ^= 1;
  }
#undef STAGE

  if (EPI == 0) {
    // Q scaled by Dh^-0.5 * log2(e) so attention softmax runs in base 2
    const float QSCALE = 0.18033688011112042f;
#pragma unroll
    for (int j = 0; j < 4; ++j) {
      const int n = n0 + wc + j*16 + (lane & 15);
      const int which = n >> 9;        // 0=q, 1=k, 2=v (uniform within this j)
      const int nn = n & 511;
      const int h = nn >> 6, d = nn & 63;
      const float bb = (which == 0) ? bq[nn] : (which == 1) ? bk[nn] : bv[nn];
#pragma unroll
      for (int i = 0; i < 4; ++i)
#pragma unroll
        for (int r = 0; r < 4; ++r) {
          const int mm = m0 + wr + i*16 + 4*(lane>>4) + r;
          const int b = mm >> 11, s = mm & 2047;
          const int bh = b*NH + h;
          const float av = acc[i][j][r] + bb;
          if (which == 0) {
            qa[(((size_t)bh*64 + (s>>5))*4 + (d>>4))*512
               + (((d>>3)&1)*32 + (s&31))*8 + (d&7)] = f2bf(av * QSCALE);
          } else if (which == 1) {
            ka[(((size_t)bh*64 + (s>>5))*4 + (d>>4))*512
               + (((d>>3)&1)*32 + (s&31))*8 + (d&7)] = f2bf(av);
          } else {
            vta[(((size_t)bh*128 + (s>>4))*2 + (d>>5))*512
               + (((s>>3)&1)*32 + (d&31))*8 + (s&7)] = f2bf(av);
          }
        }
    }
  } else {
#pragma unroll
    for (int j = 0; j < 4; ++j) {
      const int n = n0 + wc + j*16 + (lane & 15);
      const float bb = bo[n];
#pragma unroll
      for (int i = 0; i < 4; ++i)
#pragma unroll
        for (int r = 0; r < 4; ++r) {
          const int m = m0 + wr + i*16 + 4*(lane>>4) + r;
          outp[(size_t)m*ND + n] = acc[i][j][r] + bb;
        }
    }
  }
}

// ---------------- flash attention: frag-packed, no-max exp2 softmax, phase-rotated ----
// r15 + (a) pseudo-random per-block phase rotation ro=(blk*5)&31 (odd multiplier =
// permutation; desyncs co-resident blocks regardless of dispatch mapping; sum is
// commutative -> exact), (b) s_setprio(1) around MFMA clusters (T5; independent
// blocks, no barriers -> m191 regime).
__global__ __launch_bounds__(256) void attn_kernel(
    const ushort_t* __restrict__ qfv, const ushort_t* __restrict__ kfv,
    const ushort_t* __restrict__ vfv, ushort_t* __restrict__ ao)
{
  // XCD swizzle: [2:0]=bh_low3, [6:3]=qblk, [8:7]=bh_high2
  const int blk  = blockIdx.x;
  const int bh   = (blk & 7) | ((blk >> 7) << 3);
  const int qblk = (blk >> 3) & 15;
  const int ro   = (blk * 5) & 31;     // phase rotation (tile units)
  const int w    = threadIdx.x >> 6;
  const int lane = threadIdx.x & 63;
  const int lo5 = lane & 31, hi = lane >> 5;
  const int qt = qblk*4 + w;           // 32-row q tile within bh (0..63)

  const ushort_t* qb = qfv + (((size_t)bh*64 + qt)*4)*512 + lane*8;
  bf16x8 qf[4];
#pragma unroll
  for (int s = 0; s < 4; ++s) qf[s] = ld8(qb + s*512);

  const ushort_t* kb = kfv + ((size_t)bh*256)*512 + lane*8;   // + (tile*8+s)*512
  const ushort_t* vb = vfv + ((size_t)bh*256)*512 + lane*8;   // + (kv16*2+dt)*512

  f32x16 o0 = {}, o1 = {};
  float l0 = 0.f, l1 = 0.f, l2 = 0.f, l3 = 0.f;

  bf16x8 kf0[4], kf1[4];
#pragma unroll
  for (int s = 0; s < 4; ++s) {
    kf0[s] = ld8(kb + ((size_t)(ro*8) + s)*512);
    kf1[s] = ld8(kb + ((size_t)(ro*8) + 4 + s)*512);
  }

  for (int t = 0; t < 32; ++t) {
    const int idx = (t + ro) & 31;
    // V fragments for tile idx (latency hides under QK^T + softmax)
    bf16x8 vf0[4], vf1[4];
#pragma unroll
    for (int ks = 0; ks < 4; ++ks) {
      vf0[ks] = ld8(vb + ((size_t)(idx*4 + ks)*2    )*512);
      vf1[ks] = ld8(vb + ((size_t)(idx*4 + ks)*2 + 1)*512);
    }
    // QK^T (swapped): s[kv, q]
    f32x16 s0 = {}, s1 = {};
    __builtin_amdgcn_s_setprio(1);
#pragma unroll
    for (int s = 0; s < 4; ++s) {
      s0 = __builtin_amdgcn_mfma_f32_32x32x16_bf16(kf0[s], qf[s], s0, 0, 0, 0);
      s1 = __builtin_amdgcn_mfma_f32_32x32x16_bf16(kf1[s], qf[s], s1, 0, 0, 0);
    }
    __builtin_amdgcn_s_setprio(0);
    // prefetch K for next tile
    if (t < 31) {
      const int nidx = (t + 1 + ro) & 31;
#pragma unroll
      for (int s = 0; s < 4; ++s) {
        kf0[s] = ld8(kb + ((size_t)(nidx*8) + s)*512);
        kf1[s] = ld8(kb + ((size_t)(nidx*8) + 4 + s)*512);
      }
    }
    // softmax without max subtraction (scores bounded; fp32 exp2 safe)
#pragma unroll
    for (int r = 0; r < 16; r += 4) {
      s0[r]   = __builtin_amdgcn_exp2f(s0[r]);   l0 += s0[r];
      s0[r+1] = __builtin_amdgcn_exp2f(s0[r+1]); l1 += s0[r+1];
      s0[r+2] = __builtin_amdgcn_exp2f(s0[r+2]); l2 += s0[r+2];
      s0[r+3] = __builtin_amdgcn_exp2f(s0[r+3]); l3 += s0[r+3];
    }
#pragma unroll
    for (int r = 0; r < 16; r += 4) {
      s1[r]   = __builtin_amdgcn_exp2f(s1[r]);   l0 += s1[r];
      s1[r+1] = __builtin_amdgcn_exp2f(s1[r+1]); l1 += s1[r+1];
      s1[r+2] = __builtin_amdgcn_exp2f(s1[r+2]); l2 += s1[r+2];
      s1[r+3] = __builtin_amdgcn_exp2f(s1[r+3]); l3 += s1[r+3];
    }
    // P -> B-fragments in-register (cvt_pk + permlane32_swap)
    bf16x8 pf[4];
    {
      uint_t a, b, c, d;
      a = cvtpk(s0[0],  s0[1]);  b = cvtpk(s0[4],  s0[5]);  pswap(a, b);
      c = cvtpk(s0[2],  s0[3]);  d = cvtpk(s0[6],  s0[7]);  pswap(c, d);
      pf[0] = __builtin_bit_cast(bf16x8, (u32x4){a, c, b, d});
      a = cvtpk(s0[8],  s0[9]);  b = cvtpk(s0[12], s0[13]); pswap(a, b);
      c = cvtpk(s0[10], s0[11]); d = cvtpk(s0[14], s0[15]); pswap(c, d);
      pf[1] = __builtin_bit_cast(bf16x8, (u32x4){a, c, b, d});
      a = cvtpk(s1[0],  s1[1]);  b = cvtpk(s1[4],  s1[5]);  pswap(a, b);
      c = cvtpk(s1[2],  s1[3]);  d = cvtpk(s1[6],  s1[7]);  pswap(c, d);
      pf[2] = __builtin_bit_cast(bf16x8, (u32x4){a, c, b, d});
      a = cvtpk(s1[8],  s1[9]);  b = cvtpk(s1[12], s1[13]); pswap(a, b);
      c = cvtpk(s1[10], s1[11]); d = cvtpk(s1[14], s1[15]); pswap(c, d);
      pf[3] = __builtin_bit_cast(bf16x8, (u32x4){a, c, b, d});
    }
    // PV: O^T += V^T * P
    __builtin_amdgcn_s_setprio(1);
#pragma unroll
    for (int ks = 0; ks < 4; ++ks) {
      o0 = __builtin_amdgcn_mfma_f32_32x32x16_bf16(vf0[ks], pf[ks], o0, 0, 0, 0);
      o1 = __builtin_amdgcn_mfma_f32_32x32x16_bf16(vf1[ks], pf[ks], o1, 0, 0, 0);
    }
    __builtin_amdgcn_s_setprio(0);
  }

  float l = (l0 + l1) + (l2 + l3);
  l += __shfl_xor(l, 32);
  const float rl = __builtin_amdgcn_rcpf(l);
  const int b = bh >> 3, h = bh & 7;
  const int srow = qt*32 + lo5;
  ushort_t* ob = ao + ((size_t)(b*NS + srow))*ND + h*DH;
#pragma unroll
  for (int dt = 0; dt < 2; ++dt) {
    f32x16& oo = dt ? o1 : o0;
#pragma unroll
    for (int r = 0; r < 16; r += 2) {
      const int d = (r & 3) + 8*(r >> 2) + 4*hi + dt*32;
      *(uint_t*)(ob + d) = cvtpk(oo[r]*rl, oo[r+1]*rl);
    }
  }
}

extern "C" void kernel_launch(void* const* d_in, const int* in_sizes, int n_in,
                              void* d_out, int out_size, void* d_ws, size_t ws_size,
                              hipStream_t stream)
{
  const float* x  = (const float*)d_in[0];
  const float* g  = (const float*)d_in[1];
  const float* be = (const float*)d_in[2];
  const float* Wq = (const float*)d_in[3];
  const float* bq = (const float*)d_in[4];
  const float* Wk = (const float*)d_in[5];
  const float* bk = (const float*)d_in[6];
  const float* Wv = (const float*)d_in[7];
  const float* bv = (const float*)d_in[8];
  const float* Wo = (const float*)d_in[9];
  const float* bo = (const float*)d_in[10];
  float* out = (float*)d_out;

  char* w = (char*)d_ws;
  ushort_t* xn   = (ushort_t*)w; w += (size_t)MTOK*ND*2;
  ushort_t* wqkv = (ushort_t*)w; w += (size_t)1536*512*2;
  ushort_t* wob  = (ushort_t*)w; w += (size_t)512*512*2;
  ushort_t* qa   = (ushort_t*)w; w += (size_t)MTOK*ND*2;   // Q fragments
  ushort_t* ka   = (ushort_t*)w; w += (size_t)MTOK*ND*2;   // K fragments
  ushort_t* vta  = (ushort_t*)w; w += (size_t)MTOK*ND*2;   // V^T fragments
  ushort_t* ao   = (ushort_t*)w; w += (size_t)MTOK*ND*2;   // attention output (row-major)

  ln_conv<<<2560, 256, 0, stream>>>(x, g, be, xn, Wq, Wk, Wv, Wo, wqkv, wob);
  gemm_bt<0, 12><<<768, 256, 0, stream>>>(xn, wqkv, ND,
      bq, bk, bv, qa, ka, vta, nullptr, nullptr);
  attn_kernel<<<512, 256, 0, stream>>>(qa, ka, vta, ao);
  gemm_bt<1, 4><<<256, 256, 0, stream>>>(ao, wob, ND,
      nullptr, nullptr, nullptr, nullptr, nullptr, nullptr, bo, out);
}

// Round 17
// 93.379 us; speedup vs baseline: 1.0454x; 1.0454x over previous
//
#include <hip/hip_runtime.h>
#include <cstdint>
#include <cstddef>

#define NB 4
#define NS 2048
#define ND 512
#define NH 8
#define DH 64
#define MTOK (NB*NS)

typedef __bf16 bf16x8 __attribute__((ext_vector_type(8)));
typedef float f32x4 __attribute__((ext_vector_type(4)));
typedef float f32x16 __attribute__((ext_vector_type(16)));
typedef unsigned int u32x4 __attribute__((ext_vector_type(4)));
typedef unsigned short ushort_t;
typedef unsigned int uint_t;

__device__ __forceinline__ unsigned short f2bf(float f) {
  unsigned int u = __builtin_bit_cast(unsigned int, f);
  return (unsigned short)((u + 0x7fffu + ((u >> 16) & 1u)) >> 16);
}

__device__ __forceinline__ uint_t cvtpk(float lo, float hi) {
  uint_t r;
  asm("v_cvt_pk_bf16_f32 %0, %1, %2" : "=v"(r) : "v"(lo), "v"(hi));
  return r;
}

// swap lanes 32-63 of a with lanes 0-31 of b (only used on distinct values)
__device__ __forceinline__ void pswap(uint_t &a, uint_t &b) {
  asm("v_permlane32_swap_b32 %0, %1" : "+v"(a), "+v"(b));
}

__device__ __forceinline__ void gload_lds16(const void* g, void* l) {
  __builtin_amdgcn_global_load_lds(
      (const __attribute__((address_space(1))) unsigned int*)g,
      (__attribute__((address_space(3))) unsigned int*)l,
      16, 0, 0);
}

__device__ __forceinline__ bf16x8 ld8(const ushort_t* p) { return *(const bf16x8*)p; }

// ---------------- fused LayerNorm (blocks 0..2047) + weight convert (2048..2559) ----
__global__ __launch_bounds__(256) void ln_conv(
    const float* __restrict__ x, const float* __restrict__ gamma,
    const float* __restrict__ beta, ushort_t* __restrict__ xn,
    const float* __restrict__ Wq, const float* __restrict__ Wk,
    const float* __restrict__ Wv, const float* __restrict__ Wo,
    ushort_t* __restrict__ wqkv, ushort_t* __restrict__ wob)
{
  if (blockIdx.x >= 2048) {
    const int t = (blockIdx.x - 2048)*256 + threadIdx.x;
    const int i = t*8;
    const float* src; ushort_t* dst;
    if (i < 1536*512) {
      const int n = i >> 9, c = i & 511;
      const float* W = (n < 512) ? Wq : (n < 1024) ? Wk : Wv;
      src = W + ((size_t)(n & 511) << 9) + c;
      dst = wqkv + i;
    } else {
      const int jj = i - 1536*512;
      src = Wo + jj; dst = wob + jj;
    }
    float4 a = ((const float4*)src)[0], b = ((const float4*)src)[1];
    uint4 o;
    o.x = (uint_t)f2bf(a.x) | ((uint_t)f2bf(a.y)<<16);
    o.y = (uint_t)f2bf(a.z) | ((uint_t)f2bf(a.w)<<16);
    o.z = (uint_t)f2bf(b.x) | ((uint_t)f2bf(b.y)<<16);
    o.w = (uint_t)f2bf(b.z) | ((uint_t)f2bf(b.w)<<16);
    *(uint4*)dst = o;
    return;
  }
  const int row  = blockIdx.x * 4 + (threadIdx.x >> 6);
  const int lane = threadIdx.x & 63;
  const float4* xr = (const float4*)(x + (size_t)row * ND);
  float4 a = xr[lane*2], b = xr[lane*2+1];
  float v[8] = {a.x,a.y,a.z,a.w,b.x,b.y,b.z,b.w};
  float s = 0.f, s2 = 0.f;
#pragma unroll
  for (int j = 0; j < 8; ++j) { s += v[j]; s2 += v[j]*v[j]; }
#pragma unroll
  for (int mk = 1; mk < 64; mk <<= 1) { s += __shfl_xor(s, mk); s2 += __shfl_xor(s2, mk); }
  const float mu = s * (1.0f/ND);
  const float rs = rsqrtf(s2*(1.0f/ND) - mu*mu + 1e-5f);
  const float4* g4 = (const float4*)gamma;
  const float4* b4 = (const float4*)beta;
  float4 g0 = g4[lane*2], g1 = g4[lane*2+1];
  float4 e0 = b4[lane*2], e1 = b4[lane*2+1];
  float gv[8] = {g0.x,g0.y,g0.z,g0.w,g1.x,g1.y,g1.z,g1.w};
  float ev[8] = {e0.x,e0.y,e0.z,e0.w,e1.x,e1.y,e1.z,e1.w};
  unsigned short o[8];
#pragma unroll
  for (int j = 0; j < 8; ++j) o[j] = f2bf((v[j]-mu)*rs*gv[j] + ev[j]);
  uint4 ov;
  ov.x = (uint_t)o[0] | ((uint_t)o[1]<<16);
  ov.y = (uint_t)o[2] | ((uint_t)o[3]<<16);
  ov.z = (uint_t)o[4] | ((uint_t)o[5]<<16);
  ov.w = (uint_t)o[6] | ((uint_t)o[7]<<16);
  ((uint4*)(xn + (size_t)row*ND))[lane] = ov;
}

// ---------------- GEMM C[M,N] = A[M,K] * Bw[N,K]^T, 128x128 tile, BK=32 ----------------
// Double-buffered LDS; counted vmcnt; 1-D grid with XCD-bijective swizzle so each
// XCD works a contiguous m-panel band (B + A-panels fit its private L2).
// EPI==0 scatters q/k/v into fragment layouts.
template<int EPI, int NTN>
__global__ __launch_bounds__(256, 2) void gemm_bt(
    const ushort_t* __restrict__ A, const ushort_t* __restrict__ Bw, int Kd,
    const float* __restrict__ bq, const float* __restrict__ bk, const float* __restrict__ bv,
    ushort_t* __restrict__ qa, ushort_t* __restrict__ ka, ushort_t* __restrict__ vta,
    const float* __restrict__ bo, float* __restrict__ outp)
{
  __shared__ ushort_t lA[2][128*32];
  __shared__ ushort_t lB[2][128*32];
  const int tid = threadIdx.x;
  const int wave = tid >> 6, lane = tid & 63;
  const int wg = (blockIdx.x & 7) * (gridDim.x >> 3) + (blockIdx.x >> 3);
  const int m0 = (wg / NTN) * 128, n0 = (wg % NTN) * 128;
  const int wr = (wave >> 1) * 64, wc = (wave & 1) * 64;

  f32x4 acc[4][4] = {};

  const ushort_t* aS = A  + (size_t)(m0 + tid/4) * Kd + (tid & 3) * 8;
  const ushort_t* bS = Bw + (size_t)(n0 + tid/4) * Kd + (tid & 3) * 8;
  const size_t half = (size_t)64 * Kd;
  const int NT = Kd / 32;

#define STAGE(BUF, K0)                                            \
  gload_lds16(aS + (K0),        lA[BUF] + wave*512);              \
  gload_lds16(aS + half + (K0), lA[BUF] + 2048 + wave*512);       \
  gload_lds16(bS + (K0),        lB[BUF] + wave*512);              \
  gload_lds16(bS + half + (K0), lB[BUF] + 2048 + wave*512);

  STAGE(0, 0);
  int cur = 0;
  for (int t = 0; t < NT; ++t) {
    if (t + 1 < NT) {
      STAGE(cur ^ 1, (t + 1) * 32);
      asm volatile("s_waitcnt vmcnt(4)" ::: "memory");
    } else {
      asm volatile("s_waitcnt vmcnt(0)" ::: "memory");
    }
    __builtin_amdgcn_s_barrier();
    asm volatile("" ::: "memory");
    bf16x8 af[4], bfr[4];
#pragma unroll
    for (int i = 0; i < 4; ++i)
      af[i] = *(const bf16x8*)(lA[cur] + (wr + i*16 + (lane&15))*32 + (lane>>4)*8);
#pragma unroll
    for (int j = 0; j < 4; ++j)
      bfr[j] = *(const bf16x8*)(lB[cur] + (wc + j*16 + (lane&15))*32 + (lane>>4)*8);
#pragma unroll
    for (int i = 0; i < 4; ++i)
#pragma unroll
      for (int j = 0; j < 4; ++j)
        acc[i][j] = __builtin_amdgcn_mfma_f32_16x16x32_bf16(af[i], bfr[j], acc[i][j], 0, 0, 0);
    asm volatile("s_waitcnt lgkmcnt(0)" ::: "memory");
    __builtin_amdgcn_s_barrier();
    asm volatile("" ::: "memory");
    cur ^= 1;
  }
#undef STAGE

  if (EPI == 0) {
    // Q scaled by Dh^-0.5 * log2(e) so attention softmax runs in base 2
    const float QSCALE = 0.18033688011112042f;
#pragma unroll
    for (int j = 0; j < 4; ++j) {
      const int n = n0 + wc + j*16 + (lane & 15);
      const int which = n >> 9;        // 0=q, 1=k, 2=v (uniform within this j)
      const int nn = n & 511;
      const int h = nn >> 6, d = nn & 63;
      const float bb = (which == 0) ? bq[nn] : (which == 1) ? bk[nn] : bv[nn];
#pragma unroll
      for (int i = 0; i < 4; ++i)
#pragma unroll
        for (int r = 0; r < 4; ++r) {
          const int mm = m0 + wr + i*16 + 4*(lane>>4) + r;
          const int b = mm >> 11, s = mm & 2047;
          const int bh = b*NH + h;
          const float av = acc[i][j][r] + bb;
          if (which == 0) {
            qa[(((size_t)bh*64 + (s>>5))*4 + (d>>4))*512
               + (((d>>3)&1)*32 + (s&31))*8 + (d&7)] = f2bf(av * QSCALE);
          } else if (which == 1) {
            ka[(((size_t)bh*64 + (s>>5))*4 + (d>>4))*512
               + (((d>>3)&1)*32 + (s&31))*8 + (d&7)] = f2bf(av);
          } else {
            vta[(((size_t)bh*128 + (s>>4))*2 + (d>>5))*512
               + (((s>>3)&1)*32 + (d&31))*8 + (s&7)] = f2bf(av);
          }
        }
    }
  } else {
#pragma unroll
    for (int j = 0; j < 4; ++j) {
      const int n = n0 + wc + j*16 + (lane & 15);
      const float bb = bo[n];
#pragma unroll
      for (int i = 0; i < 4; ++i)
#pragma unroll
        for (int r = 0; r < 4; ++r) {
          const int m = m0 + wr + i*16 + 4*(lane>>4) + r;
          outp[(size_t)m*ND + n] = acc[i][j][r] + bb;
        }
    }
  }
}

// ---------------- flash attention: frag-packed, no-max exp2 softmax, phase-rotated ----
// r6 body (grid 512, 2 blocks/CU). Blocks 256..511 walk the 32 kv tiles with a
// 16-tile rotation: co-resident blocks (round-robin dispatch pairs blk, blk+256)
// sit half a sweep apart, so one block's exp2/pack [VALU] overlaps the other's
// QK/PV [MFMA] instead of colliding in lockstep. Sum is commutative -> exact.
__global__ __launch_bounds__(256) void attn_kernel(
    const ushort_t* __restrict__ qfv, const ushort_t* __restrict__ kfv,
    const ushort_t* __restrict__ vfv, ushort_t* __restrict__ ao)
{
  // XCD swizzle: [2:0]=bh_low3, [6:3]=qblk, [8:7]=bh_high2
  const int blk  = blockIdx.x;
  const int bh   = (blk & 7) | ((blk >> 7) << 3);
  const int qblk = (blk >> 3) & 15;
  const int ro   = (blk >> 8) & 1 ? 16 : 0;   // phase rotation (tile units)
  const int w    = threadIdx.x >> 6;
  const int lane = threadIdx.x & 63;
  const int lo5 = lane & 31, hi = lane >> 5;
  const int qt = qblk*4 + w;           // 32-row q tile within bh (0..63)

  const ushort_t* qb = qfv + (((size_t)bh*64 + qt)*4)*512 + lane*8;
  bf16x8 qf[4];
#pragma unroll
  for (int s = 0; s < 4; ++s) qf[s] = ld8(qb + s*512);

  const ushort_t* kb = kfv + ((size_t)bh*256)*512 + lane*8;   // + (tile*8+s)*512
  const ushort_t* vb = vfv + ((size_t)bh*256)*512 + lane*8;   // + (kv16*2+dt)*512

  f32x16 o0 = {}, o1 = {};
  float l0 = 0.f, l1 = 0.f, l2 = 0.f, l3 = 0.f;

  bf16x8 kf0[4], kf1[4];
#pragma unroll
  for (int s = 0; s < 4; ++s) {
    kf0[s] = ld8(kb + ((size_t)(ro*8) + s)*512);
    kf1[s] = ld8(kb + ((size_t)(ro*8) + 4 + s)*512);
  }

  for (int t = 0; t < 32; ++t) {
    const int idx = (t + ro) & 31;
    // V fragments for tile idx (latency hides under QK^T + softmax)
    bf16x8 vf0[4], vf1[4];
#pragma unroll
    for (int ks = 0; ks < 4; ++ks) {
      vf0[ks] = ld8(vb + ((size_t)(idx*4 + ks)*2    )*512);
      vf1[ks] = ld8(vb + ((size_t)(idx*4 + ks)*2 + 1)*512);
    }
    // QK^T (swapped): s[kv, q]
    f32x16 s0 = {}, s1 = {};
#pragma unroll
    for (int s = 0; s < 4; ++s) {
      s0 = __builtin_amdgcn_mfma_f32_32x32x16_bf16(kf0[s], qf[s], s0, 0, 0, 0);
      s1 = __builtin_amdgcn_mfma_f32_32x32x16_bf16(kf1[s], qf[s], s1, 0, 0, 0);
    }
    // prefetch K for next tile
    if (t < 31) {
      const int nidx = (t + 1 + ro) & 31;
#pragma unroll
      for (int s = 0; s < 4; ++s) {
        kf0[s] = ld8(kb + ((size_t)(nidx*8) + s)*512);
        kf1[s] = ld8(kb + ((size_t)(nidx*8) + 4 + s)*512);
      }
    }
    // softmax without max subtraction (scores bounded; fp32 exp2 safe)
#pragma unroll
    for (int r = 0; r < 16; r += 4) {
      s0[r]   = __builtin_amdgcn_exp2f(s0[r]);   l0 += s0[r];
      s0[r+1] = __builtin_amdgcn_exp2f(s0[r+1]); l1 += s0[r+1];
      s0[r+2] = __builtin_amdgcn_exp2f(s0[r+2]); l2 += s0[r+2];
      s0[r+3] = __builtin_amdgcn_exp2f(s0[r+3]); l3 += s0[r+3];
    }
#pragma unroll
    for (int r = 0; r < 16; r += 4) {
      s1[r]   = __builtin_amdgcn_exp2f(s1[r]);   l0 += s1[r];
      s1[r+1] = __builtin_amdgcn_exp2f(s1[r+1]); l1 += s1[r+1];
      s1[r+2] = __builtin_amdgcn_exp2f(s1[r+2]); l2 += s1[r+2];
      s1[r+3] = __builtin_amdgcn_exp2f(s1[r+3]); l3 += s1[r+3];
    }
    // P -> B-fragments in-register (cvt_pk + permlane32_swap)
    bf16x8 pf[4];
    {
      uint_t a, b, c, d;
      a = cvtpk(s0[0],  s0[1]);  b = cvtpk(s0[4],  s0[5]);  pswap(a, b);
      c = cvtpk(s0[2],  s0[3]);  d = cvtpk(s0[6],  s0[7]);  pswap(c, d);
      pf[0] = __builtin_bit_cast(bf16x8, (u32x4){a, c, b, d});
      a = cvtpk(s0[8],  s0[9]);  b = cvtpk(s0[12], s0[13]); pswap(a, b);
      c = cvtpk(s0[10], s0[11]); d = cvtpk(s0[14], s0[15]); pswap(c, d);
      pf[1] = __builtin_bit_cast(bf16x8, (u32x4){a, c, b, d});
      a = cvtpk(s1[0],  s1[1]);  b = cvtpk(s1[4],  s1[5]);  pswap(a, b);
      c = cvtpk(s1[2],  s1[3]);  d = cvtpk(s1[6],  s1[7]);  pswap(c, d);
      pf[2] = __builtin_bit_cast(bf16x8, (u32x4){a, c, b, d});
      a = cvtpk(s1[8],  s1[9]);  b = cvtpk(s1[12], s1[13]); pswap(a, b);
      c = cvtpk(s1[10], s1[11]); d = cvtpk(s1[14], s1[15]); pswap(c, d);
      pf[3] = __builtin_bit_cast(bf16x8, (u32x4){a, c, b, d});
    }
    // PV: O^T += V^T * P
#pragma unroll
    for (int ks = 0; ks < 4; ++ks) {
      o0 = __builtin_amdgcn_mfma_f32_32x32x16_bf16(vf0[ks], pf[ks], o0, 0, 0, 0);
      o1 = __builtin_amdgcn_mfma_f32_32x32x16_bf16(vf1[ks], pf[ks], o1, 0, 0, 0);
    }
  }

  float l = (l0 + l1) + (l2 + l3);
  l += __shfl_xor(l, 32);
  const float rl = __builtin_amdgcn_rcpf(l);
  const int b = bh >> 3, h = bh & 7;
  const int srow = qt*32 + lo5;
  ushort_t* ob = ao + ((size_t)(b*NS + srow))*ND + h*DH;
#pragma unroll
  for (int dt = 0; dt < 2; ++dt) {
    f32x16& oo = dt ? o1 : o0;
#pragma unroll
    for (int r = 0; r < 16; r += 2) {
      const int d = (r & 3) + 8*(r >> 2) + 4*hi + dt*32;
      *(uint_t*)(ob + d) = cvtpk(oo[r]*rl, oo[r+1]*rl);
    }
  }
}

extern "C" void kernel_launch(void* const* d_in, const int* in_sizes, int n_in,
                              void* d_out, int out_size, void* d_ws, size_t ws_size,
                              hipStream_t stream)
{
  const float* x  = (const float*)d_in[0];
  const float* g  = (const float*)d_in[1];
  const float* be = (const float*)d_in[2];
  const float* Wq = (const float*)d_in[3];
  const float* bq = (const float*)d_in[4];
  const float* Wk = (const float*)d_in[5];
  const float* bk = (const float*)d_in[6];
  const float* Wv = (const float*)d_in[7];
  const float* bv = (const float*)d_in[8];
  const float* Wo = (const float*)d_in[9];
  const float* bo = (const float*)d_in[10];
  float* out = (float*)d_out;

  char* w = (char*)d_ws;
  ushort_t* xn   = (ushort_t*)w; w += (size_t)MTOK*ND*2;
  ushort_t* wqkv = (ushort_t*)w; w += (size_t)1536*512*2;
  ushort_t* wob  = (ushort_t*)w; w += (size_t)512*512*2;
  ushort_t* qa   = (ushort_t*)w; w += (size_t)MTOK*ND*2;   // Q fragments
  ushort_t* ka   = (ushort_t*)w; w += (size_t)MTOK*ND*2;   // K fragments
  ushort_t* vta  = (ushort_t*)w; w += (size_t)MTOK*ND*2;   // V^T fragments
  ushort_t* ao   = (ushort_t*)w; w += (size_t)MTOK*ND*2;   // attention output (row-major)

  ln_conv<<<2560, 256, 0, stream>>>(x, g, be, xn, Wq, Wk, Wv, Wo, wqkv, wob);
  gemm_bt<0, 12><<<768, 256, 0, stream>>>(xn, wqkv, ND,
      bq, bk, bv, qa, ka, vta, nullptr, nullptr);
  attn_kernel<<<512, 256, 0, stream>>>(qa, ka, vta, ao);
  gemm_bt<1, 4><<<256, 256, 0, stream>>>(ao, wob, ND,
      nullptr, nullptr, nullptr, nullptr, nullptr, nullptr, bo, out);
}

// Round 18
// 90.898 us; speedup vs baseline: 1.0740x; 1.0273x over previous
//
#include <hip/hip_runtime.h>
#include <cstdint>
#include <cstddef>

#define NB 4
#define NS 2048
#define ND 512
#define NH 8
#define DH 64
#define MTOK (NB*NS)

typedef __bf16 bf16x8 __attribute__((ext_vector_type(8)));
typedef float f32x4 __attribute__((ext_vector_type(4)));
typedef float f32x16 __attribute__((ext_vector_type(16)));
typedef unsigned int u32x4 __attribute__((ext_vector_type(4)));
typedef unsigned short ushort_t;
typedef unsigned int uint_t;

__device__ __forceinline__ unsigned short f2bf(float f) {
  unsigned int u = __builtin_bit_cast(unsigned int, f);
  return (unsigned short)((u + 0x7fffu + ((u >> 16) & 1u)) >> 16);
}

__device__ __forceinline__ uint_t cvtpk(float lo, float hi) {
  uint_t r;
  asm("v_cvt_pk_bf16_f32 %0, %1, %2" : "=v"(r) : "v"(lo), "v"(hi));
  return r;
}

// swap lanes 32-63 of a with lanes 0-31 of b (only used on distinct values)
__device__ __forceinline__ void pswap(uint_t &a, uint_t &b) {
  asm("v_permlane32_swap_b32 %0, %1" : "+v"(a), "+v"(b));
}

__device__ __forceinline__ void gload_lds16(const void* g, void* l) {
  __builtin_amdgcn_global_load_lds(
      (const __attribute__((address_space(1))) unsigned int*)g,
      (__attribute__((address_space(3))) unsigned int*)l,
      16, 0, 0);
}

__device__ __forceinline__ bf16x8 ld8(const ushort_t* p) { return *(const bf16x8*)p; }

// ---------------- fused LayerNorm (blocks 0..2047) + weight convert (2048..2559) ----
__global__ __launch_bounds__(256) void ln_conv(
    const float* __restrict__ x, const float* __restrict__ gamma,
    const float* __restrict__ beta, ushort_t* __restrict__ xn,
    const float* __restrict__ Wq, const float* __restrict__ Wk,
    const float* __restrict__ Wv, const float* __restrict__ Wo,
    ushort_t* __restrict__ wqkv, ushort_t* __restrict__ wob)
{
  if (blockIdx.x >= 2048) {
    const int t = (blockIdx.x - 2048)*256 + threadIdx.x;
    const int i = t*8;
    const float* src; ushort_t* dst;
    if (i < 1536*512) {
      const int n = i >> 9, c = i & 511;
      const float* W = (n < 512) ? Wq : (n < 1024) ? Wk : Wv;
      src = W + ((size_t)(n & 511) << 9) + c;
      dst = wqkv + i;
    } else {
      const int jj = i - 1536*512;
      src = Wo + jj; dst = wob + jj;
    }
    float4 a = ((const float4*)src)[0], b = ((const float4*)src)[1];
    uint4 o;
    o.x = (uint_t)f2bf(a.x) | ((uint_t)f2bf(a.y)<<16);
    o.y = (uint_t)f2bf(a.z) | ((uint_t)f2bf(a.w)<<16);
    o.z = (uint_t)f2bf(b.x) | ((uint_t)f2bf(b.y)<<16);
    o.w = (uint_t)f2bf(b.z) | ((uint_t)f2bf(b.w)<<16);
    *(uint4*)dst = o;
    return;
  }
  const int row  = blockIdx.x * 4 + (threadIdx.x >> 6);
  const int lane = threadIdx.x & 63;
  const float4* xr = (const float4*)(x + (size_t)row * ND);
  float4 a = xr[lane*2], b = xr[lane*2+1];
  float v[8] = {a.x,a.y,a.z,a.w,b.x,b.y,b.z,b.w};
  float s = 0.f, s2 = 0.f;
#pragma unroll
  for (int j = 0; j < 8; ++j) { s += v[j]; s2 += v[j]*v[j]; }
#pragma unroll
  for (int mk = 1; mk < 64; mk <<= 1) { s += __shfl_xor(s, mk); s2 += __shfl_xor(s2, mk); }
  const float mu = s * (1.0f/ND);
  const float rs = rsqrtf(s2*(1.0f/ND) - mu*mu + 1e-5f);
  const float4* g4 = (const float4*)gamma;
  const float4* b4 = (const float4*)beta;
  float4 g0 = g4[lane*2], g1 = g4[lane*2+1];
  float4 e0 = b4[lane*2], e1 = b4[lane*2+1];
  float gv[8] = {g0.x,g0.y,g0.z,g0.w,g1.x,g1.y,g1.z,g1.w};
  float ev[8] = {e0.x,e0.y,e0.z,e0.w,e1.x,e1.y,e1.z,e1.w};
  unsigned short o[8];
#pragma unroll
  for (int j = 0; j < 8; ++j) o[j] = f2bf((v[j]-mu)*rs*gv[j] + ev[j]);
  uint4 ov;
  ov.x = (uint_t)o[0] | ((uint_t)o[1]<<16);
  ov.y = (uint_t)o[2] | ((uint_t)o[3]<<16);
  ov.z = (uint_t)o[4] | ((uint_t)o[5]<<16);
  ov.w = (uint_t)o[6] | ((uint_t)o[7]<<16);
  ((uint4*)(xn + (size_t)row*ND))[lane] = ov;
}

// ---------------- GEMM C[M,N] = A[M,K] * Bw[N,K]^T, 128x128 tile, BK=32 ----------------
// Double-buffered LDS; counted vmcnt; 1-D grid with XCD-bijective swizzle so each
// XCD works a contiguous m-panel band (B + A-panels fit its private L2).
// EPI==0 scatters q/k/v into fragment layouts.
template<int EPI, int NTN>
__global__ __launch_bounds__(256, 2) void gemm_bt(
    const ushort_t* __restrict__ A, const ushort_t* __restrict__ Bw, int Kd,
    const float* __restrict__ bq, const float* __restrict__ bk, const float* __restrict__ bv,
    ushort_t* __restrict__ qa, ushort_t* __restrict__ ka, ushort_t* __restrict__ vta,
    const float* __restrict__ bo, float* __restrict__ outp)
{
  __shared__ ushort_t lA[2][128*32];
  __shared__ ushort_t lB[2][128*32];
  const int tid = threadIdx.x;
  const int wave = tid >> 6, lane = tid & 63;
  const int wg = (blockIdx.x & 7) * (gridDim.x >> 3) + (blockIdx.x >> 3);
  const int m0 = (wg / NTN) * 128, n0 = (wg % NTN) * 128;
  const int wr = (wave >> 1) * 64, wc = (wave & 1) * 64;

  f32x4 acc[4][4] = {};

  const ushort_t* aS = A  + (size_t)(m0 + tid/4) * Kd + (tid & 3) * 8;
  const ushort_t* bS = Bw + (size_t)(n0 + tid/4) * Kd + (tid & 3) * 8;
  const size_t half = (size_t)64 * Kd;
  const int NT = Kd / 32;

#define STAGE(BUF, K0)                                            \
  gload_lds16(aS + (K0),        lA[BUF] + wave*512);              \
  gload_lds16(aS + half + (K0), lA[BUF] + 2048 + wave*512);       \
  gload_lds16(bS + (K0),        lB[BUF] + wave*512);              \
  gload_lds16(bS + half + (K0), lB[BUF] + 2048 + wave*512);

  STAGE(0, 0);
  int cur = 0;
  for (int t = 0; t < NT; ++t) {
    if (t + 1 < NT) {
      STAGE(cur ^ 1, (t + 1) * 32);
      asm volatile("s_waitcnt vmcnt(4)" ::: "memory");
    } else {
      asm volatile("s_waitcnt vmcnt(0)" ::: "memory");
    }
    __builtin_amdgcn_s_barrier();
    asm volatile("" ::: "memory");
    bf16x8 af[4], bfr[4];
#pragma unroll
    for (int i = 0; i < 4; ++i)
      af[i] = *(const bf16x8*)(lA[cur] + (wr + i*16 + (lane&15))*32 + (lane>>4)*8);
#pragma unroll
    for (int j = 0; j < 4; ++j)
      bfr[j] = *(const bf16x8*)(lB[cur] + (wc + j*16 + (lane&15))*32 + (lane>>4)*8);
#pragma unroll
    for (int i = 0; i < 4; ++i)
#pragma unroll
      for (int j = 0; j < 4; ++j)
        acc[i][j] = __builtin_amdgcn_mfma_f32_16x16x32_bf16(af[i], bfr[j], acc[i][j], 0, 0, 0);
    asm volatile("s_waitcnt lgkmcnt(0)" ::: "memory");
    __builtin_amdgcn_s_barrier();
    asm volatile("" ::: "memory");
    cur ^= 1;
  }
#undef STAGE

  if (EPI == 0) {
    // Q scaled by Dh^-0.5 * log2(e) so attention softmax runs in base 2
    const float QSCALE = 0.18033688011112042f;
#pragma unroll
    for (int j = 0; j < 4; ++j) {
      const int n = n0 + wc + j*16 + (lane & 15);
      const int which = n >> 9;        // 0=q, 1=k, 2=v (uniform within this j)
      const int nn = n & 511;
      const int h = nn >> 6, d = nn & 63;
      const float bb = (which == 0) ? bq[nn] : (which == 1) ? bk[nn] : bv[nn];
#pragma unroll
      for (int i = 0; i < 4; ++i)
#pragma unroll
        for (int r = 0; r < 4; ++r) {
          const int mm = m0 + wr + i*16 + 4*(lane>>4) + r;
          const int b = mm >> 11, s = mm & 2047;
          const int bh = b*NH + h;
          const float av = acc[i][j][r] + bb;
          if (which == 0) {
            qa[(((size_t)bh*64 + (s>>5))*4 + (d>>4))*512
               + (((d>>3)&1)*32 + (s&31))*8 + (d&7)] = f2bf(av * QSCALE);
          } else if (which == 1) {
            ka[(((size_t)bh*64 + (s>>5))*4 + (d>>4))*512
               + (((d>>3)&1)*32 + (s&31))*8 + (d&7)] = f2bf(av);
          } else {
            vta[(((size_t)bh*128 + (s>>4))*2 + (d>>5))*512
               + (((s>>3)&1)*32 + (d&31))*8 + (s&7)] = f2bf(av);
          }
        }
    }
  } else {
#pragma unroll
    for (int j = 0; j < 4; ++j) {
      const int n = n0 + wc + j*16 + (lane & 15);
      const float bb = bo[n];
#pragma unroll
      for (int i = 0; i < 4; ++i)
#pragma unroll
        for (int r = 0; r < 4; ++r) {
          const int m = m0 + wr + i*16 + 4*(lane>>4) + r;
          outp[(size_t)m*ND + n] = acc[i][j][r] + bb;
        }
    }
  }
}

// ---------------- flash attention: frag-packed, no-max exp2 softmax, phase-rotated ----
// r15 base + odd-multiplier phase rotation ro=(blk*5)&31: every co-resident block
// pair gets a distinct phase offset regardless of the dispatch mapping, so one
// block's exp2/pack [VALU] overlaps another's QK/PV [MFMA]. Sum commutative -> exact.
// (r16's regression isolated to s_setprio, which is NOT present here.)
__global__ __launch_bounds__(256) void attn_kernel(
    const ushort_t* __restrict__ qfv, const ushort_t* __restrict__ kfv,
    const ushort_t* __restrict__ vfv, ushort_t* __restrict__ ao)
{
  // XCD swizzle: [2:0]=bh_low3, [6:3]=qblk, [8:7]=bh_high2
  const int blk  = blockIdx.x;
  const int bh   = (blk & 7) | ((blk >> 7) << 3);
  const int qblk = (blk >> 3) & 15;
  const int ro   = (blk * 5) & 31;     // phase rotation (tile units)
  const int w    = threadIdx.x >> 6;
  const int lane = threadIdx.x & 63;
  const int lo5 = lane & 31, hi = lane >> 5;
  const int qt = qblk*4 + w;           // 32-row q tile within bh (0..63)

  const ushort_t* qb = qfv + (((size_t)bh*64 + qt)*4)*512 + lane*8;
  bf16x8 qf[4];
#pragma unroll
  for (int s = 0; s < 4; ++s) qf[s] = ld8(qb + s*512);

  const ushort_t* kb = kfv + ((size_t)bh*256)*512 + lane*8;   // + (tile*8+s)*512
  const ushort_t* vb = vfv + ((size_t)bh*256)*512 + lane*8;   // + (kv16*2+dt)*512

  f32x16 o0 = {}, o1 = {};
  float l0 = 0.f, l1 = 0.f, l2 = 0.f, l3 = 0.f;

  bf16x8 kf0[4], kf1[4];
#pragma unroll
  for (int s = 0; s < 4; ++s) {
    kf0[s] = ld8(kb + ((size_t)(ro*8) + s)*512);
    kf1[s] = ld8(kb + ((size_t)(ro*8) + 4 + s)*512);
  }

  for (int t = 0; t < 32; ++t) {
    const int idx = (t + ro) & 31;
    // V fragments for tile idx (latency hides under QK^T + softmax)
    bf16x8 vf0[4], vf1[4];
#pragma unroll
    for (int ks = 0; ks < 4; ++ks) {
      vf0[ks] = ld8(vb + ((size_t)(idx*4 + ks)*2    )*512);
      vf1[ks] = ld8(vb + ((size_t)(idx*4 + ks)*2 + 1)*512);
    }
    // QK^T (swapped): s[kv, q]
    f32x16 s0 = {}, s1 = {};
#pragma unroll
    for (int s = 0; s < 4; ++s) {
      s0 = __builtin_amdgcn_mfma_f32_32x32x16_bf16(kf0[s], qf[s], s0, 0, 0, 0);
      s1 = __builtin_amdgcn_mfma_f32_32x32x16_bf16(kf1[s], qf[s], s1, 0, 0, 0);
    }
    // prefetch K for next tile
    if (t < 31) {
      const int nidx = (t + 1 + ro) & 31;
#pragma unroll
      for (int s = 0; s < 4; ++s) {
        kf0[s] = ld8(kb + ((size_t)(nidx*8) + s)*512);
        kf1[s] = ld8(kb + ((size_t)(nidx*8) + 4 + s)*512);
      }
    }
    // softmax without max subtraction (scores bounded; fp32 exp2 safe)
#pragma unroll
    for (int r = 0; r < 16; r += 4) {
      s0[r]   = __builtin_amdgcn_exp2f(s0[r]);   l0 += s0[r];
      s0[r+1] = __builtin_amdgcn_exp2f(s0[r+1]); l1 += s0[r+1];
      s0[r+2] = __builtin_amdgcn_exp2f(s0[r+2]); l2 += s0[r+2];
      s0[r+3] = __builtin_amdgcn_exp2f(s0[r+3]); l3 += s0[r+3];
    }
#pragma unroll
    for (int r = 0; r < 16; r += 4) {
      s1[r]   = __builtin_amdgcn_exp2f(s1[r]);   l0 += s1[r];
      s1[r+1] = __builtin_amdgcn_exp2f(s1[r+1]); l1 += s1[r+1];
      s1[r+2] = __builtin_amdgcn_exp2f(s1[r+2]); l2 += s1[r+2];
      s1[r+3] = __builtin_amdgcn_exp2f(s1[r+3]); l3 += s1[r+3];
    }
    // P -> B-fragments in-register (cvt_pk + permlane32_swap)
    bf16x8 pf[4];
    {
      uint_t a, b, c, d;
      a = cvtpk(s0[0],  s0[1]);  b = cvtpk(s0[4],  s0[5]);  pswap(a, b);
      c = cvtpk(s0[2],  s0[3]);  d = cvtpk(s0[6],  s0[7]);  pswap(c, d);
      pf[0] = __builtin_bit_cast(bf16x8, (u32x4){a, c, b, d});
      a = cvtpk(s0[8],  s0[9]);  b = cvtpk(s0[12], s0[13]); pswap(a, b);
      c = cvtpk(s0[10], s0[11]); d = cvtpk(s0[14], s0[15]); pswap(c, d);
      pf[1] = __builtin_bit_cast(bf16x8, (u32x4){a, c, b, d});
      a = cvtpk(s1[0],  s1[1]);  b = cvtpk(s1[4],  s1[5]);  pswap(a, b);
      c = cvtpk(s1[2],  s1[3]);  d = cvtpk(s1[6],  s1[7]);  pswap(c, d);
      pf[2] = __builtin_bit_cast(bf16x8, (u32x4){a, c, b, d});
      a = cvtpk(s1[8],  s1[9]);  b = cvtpk(s1[12], s1[13]); pswap(a, b);
      c = cvtpk(s1[10], s1[11]); d = cvtpk(s1[14], s1[15]); pswap(c, d);
      pf[3] = __builtin_bit_cast(bf16x8, (u32x4){a, c, b, d});
    }
    // PV: O^T += V^T * P
#pragma unroll
    for (int ks = 0; ks < 4; ++ks) {
      o0 = __builtin_amdgcn_mfma_f32_32x32x16_bf16(vf0[ks], pf[ks], o0, 0, 0, 0);
      o1 = __builtin_amdgcn_mfma_f32_32x32x16_bf16(vf1[ks], pf[ks], o1, 0, 0, 0);
    }
  }

  float l = (l0 + l1) + (l2 + l3);
  l += __shfl_xor(l, 32);
  const float rl = __builtin_amdgcn_rcpf(l);
  const int b = bh >> 3, h = bh & 7;
  const int srow = qt*32 + lo5;
  ushort_t* ob = ao + ((size_t)(b*NS + srow))*ND + h*DH;
#pragma unroll
  for (int dt = 0; dt < 2; ++dt) {
    f32x16& oo = dt ? o1 : o0;
#pragma unroll
    for (int r = 0; r < 16; r += 2) {
      const int d = (r & 3) + 8*(r >> 2) + 4*hi + dt*32;
      *(uint_t*)(ob + d) = cvtpk(oo[r]*rl, oo[r+1]*rl);
    }
  }
}

extern "C" void kernel_launch(void* const* d_in, const int* in_sizes, int n_in,
                              void* d_out, int out_size, void* d_ws, size_t ws_size,
                              hipStream_t stream)
{
  const float* x  = (const float*)d_in[0];
  const float* g  = (const float*)d_in[1];
  const float* be = (const float*)d_in[2];
  const float* Wq = (const float*)d_in[3];
  const float* bq = (const float*)d_in[4];
  const float* Wk = (const float*)d_in[5];
  const float* bk = (const float*)d_in[6];
  const float* Wv = (const float*)d_in[7];
  const float* bv = (const float*)d_in[8];
  const float* Wo = (const float*)d_in[9];
  const float* bo = (const float*)d_in[10];
  float* out = (float*)d_out;

  char* w = (char*)d_ws;
  ushort_t* xn   = (ushort_t*)w; w += (size_t)MTOK*ND*2;
  ushort_t* wqkv = (ushort_t*)w; w += (size_t)1536*512*2;
  ushort_t* wob  = (ushort_t*)w; w += (size_t)512*512*2;
  ushort_t* qa   = (ushort_t*)w; w += (size_t)MTOK*ND*2;   // Q fragments
  ushort_t* ka   = (ushort_t*)w; w += (size_t)MTOK*ND*2;   // K fragments
  ushort_t* vta  = (ushort_t*)w; w += (size_t)MTOK*ND*2;   // V^T fragments
  ushort_t* ao   = (ushort_t*)w; w += (size_t)MTOK*ND*2;   // attention output (row-major)

  ln_conv<<<2560, 256, 0, stream>>>(x, g, be, xn, Wq, Wk, Wv, Wo, wqkv, wob);
  gemm_bt<0, 12><<<768, 256, 0, stream>>>(xn, wqkv, ND,
      bq, bk, bv, qa, ka, vta, nullptr, nullptr);
  attn_kernel<<<512, 256, 0, stream>>>(qa, ka, vta, ao);
  gemm_bt<1, 4><<<256, 256, 0, stream>>>(ao, wob, ND,
      nullptr, nullptr, nullptr, nullptr, nullptr, nullptr, bo, out);
}